// Round 1
// baseline (227.940 us; speedup 1.0000x reference)
//
#include <hip/hip_runtime.h>
#include <math.h>

#define DEVI __device__ __forceinline__

constexpr int B = 2, P = 16, G = 128, E = 96, N = 128, CO = 2;

DEVI float lrelu(float x) { return x > 0.f ? x : 0.01f * x; }

// ---- workspace layout (in floats) ----
constexpr int OFF_U      = 0;                      // B*N*P*G
constexpr int OFF_V      = OFF_U + B * N * P * G;  // B*N*G*E
constexpr int OFF_S110   = OFF_V + B * N * G * E;  // B*N*P*G
constexpr int OFF_S011   = OFF_S110 + B * N * P * G; // B*N*G*E
constexpr int OFF_S001   = OFF_S011 + B * N * G * E; // B*N*E
constexpr int OFF_MAXEV  = OFF_S001 + B * N * E;   // B*N*G
constexpr int OFF_MAXPU  = OFF_MAXEV + B * N * G;  // B*N*G
constexpr int OFF_RMP110 = OFF_MAXPU + B * N * G;  // B*4*G
constexpr int OFF_RMG110 = OFF_RMP110 + B * 4 * G; // B*4*P
constexpr int OFF_RME011 = OFF_RMG110 + B * 4 * P; // B*2*G
constexpr int OFF_RMG011 = OFF_RME011 + B * 2 * G; // B*2*E
constexpr int OFF_MP110  = OFF_RMG011 + B * 2 * E; // B*N*G
constexpr int OFF_MG110  = OFF_MP110 + B * N * G;  // B*N*P
constexpr int OFF_MG011  = OFF_MG110 + B * N * P;  // B*N*E
constexpr int OFF_ME011  = OFF_MG011 + B * N * E;  // B*N*G
constexpr int OFF_C1P    = OFF_ME011 + B * N * G;  // B*N*P
constexpr int OFF_BF1G   = OFF_C1P + B * N * P;    // B*N*G
constexpr int OFF_EG1E   = OFF_BF1G + B * N * G;   // B*N*E
constexpr int OFF_M110   = OFF_EG1E + B * N * E;   // B*N*P
constexpr int OFF_M011E  = OFF_M110 + B * N * P;   // B*N*E

// ---------------------------------------------------------------------------
// K0: reductions of raw inputs (all tiny). 2048 threads total.
__global__ void k_in_reduce(const float* __restrict__ x110,
                            const float* __restrict__ x011,
                            float* __restrict__ rmp110, float* __restrict__ rmg110,
                            float* __restrict__ rme011, float* __restrict__ rmg011) {
  int t = blockIdx.x * 256 + threadIdx.x;
  if (t < 1024) {                      // rmp110[b,c,g] = max_p x110
    int g = t & 127, c = (t >> 7) & 3, b = t >> 9;
    const float* base = x110 + ((b * 4 + c) * P) * G + g;
    float m = -INFINITY;
    for (int p = 0; p < P; p++) m = fmaxf(m, base[p * G]);
    rmp110[t] = m;
  } else if (t < 1152) {               // rmg110[b,c,p] = max_g x110
    int i = t - 1024;
    int p = i & 15, c = (i >> 4) & 3, b = i >> 6;
    const float* base = x110 + ((b * 4 + c) * P + p) * G;
    float m = -INFINITY;
    for (int g = 0; g < G; g++) m = fmaxf(m, base[g]);
    rmg110[i] = m;
  } else if (t < 1664) {               // rme011[b,c,g] = max_e x011
    int i = t - 1152;
    int g = i & 127, c = (i >> 7) & 1, b = i >> 8;
    const float* base = x011 + ((b * 2 + c) * G + g) * E;
    float m = -INFINITY;
    for (int e = 0; e < E; e++) m = fmaxf(m, base[e]);
    rme011[i] = m;
  } else if (t < 2048) {               // rmg011[b,c,e] = max_g x011
    int i = t - 1664;
    int e = i % 96; int r = i / 96; int c = r & 1, b = r >> 1;
    const float* base = x011 + ((b * 2 + c) * G) * E + e;
    float m = -INFINITY;
    for (int g = 0; g < G; g++) m = fmaxf(m, base[g * E]);
    rmg011[i] = m;
  }
}

// K1: U0[b,n,p,g]   (524288 threads, g fastest -> coalesced)
__global__ void k_U0(const float* __restrict__ x110, const float* __restrict__ W0_110,
                     const float* __restrict__ b0_110, const float* __restrict__ W0_011,
                     const float* __restrict__ b0_011, const float* __restrict__ rmp110,
                     const float* __restrict__ rmg110, const float* __restrict__ rme011,
                     float* __restrict__ U) {
  int t = blockIdx.x * 256 + threadIdx.x;
  int g = t & 127, p = (t >> 7) & 15, n = (t >> 11) & 127, b = t >> 18;
  float acc = b0_110[n] + b0_110[N + n] + b0_110[2 * N + n] + b0_011[2 * N + n];
#pragma unroll
  for (int c = 0; c < 4; c++) {
    acc += W0_110[n * 4 + c]           * x110[((b * 4 + c) * P + p) * G + g];
    acc += W0_110[(N + n) * 4 + c]     * rmp110[(b * 4 + c) * G + g];
    acc += W0_110[(2 * N + n) * 4 + c] * rmg110[(b * 4 + c) * P + p];
  }
#pragma unroll
  for (int c = 0; c < 2; c++)
    acc += W0_011[(2 * N + n) * 2 + c] * rme011[(b * 2 + c) * G + g];
  U[t] = acc;
}

// K2: V0[b,n,g,e]   (3145728 threads, e fastest)
__global__ void k_V0(const float* __restrict__ x011, const float* __restrict__ x001,
                     const float* __restrict__ W0_011, const float* __restrict__ b0_011,
                     const float* __restrict__ W0_001, const float* __restrict__ b0_001,
                     const float* __restrict__ rmg011, float* __restrict__ V) {
  int t = blockIdx.x * 256 + threadIdx.x;
  int e = t % 96; int r = t / 96;
  int g = r & 127, n = (r >> 7) & 127, b = r >> 14;
  float acc = b0_011[n] + b0_011[N + n] + b0_001[n];
#pragma unroll
  for (int c = 0; c < 2; c++) {
    acc += W0_011[n * 2 + c]       * x011[((b * 2 + c) * G + g) * E + e];
    acc += W0_011[(N + n) * 2 + c] * rmg011[(b * 2 + c) * E + e];
  }
  acc += W0_001[n] * x001[b * E + e];
  V[t] = acc;
}

// K3/K10: maxeV[b,n,g] = max_e V ; maxpU[b,n,g] = max_p U   (65536 threads)
__global__ void k_max(const float* __restrict__ U, const float* __restrict__ V,
                      float* __restrict__ maxeV, float* __restrict__ maxpU) {
  int t = blockIdx.x * 256 + threadIdx.x;
  if (t < B * N * G) {                 // t = (b*N+n)*G+g directly
    const float* base = V + (size_t)t * E;
    float m = -INFINITY;
    for (int e = 0; e < E; e++) m = fmaxf(m, base[e]);
    maxeV[t] = m;
  } else {
    int i = t - B * N * G;
    int g = i & 127; int bn = i >> 7;
    const float* base = U + ((size_t)bn * P) * G + g;
    float m = -INFINITY;
    for (int p = 0; p < P; p++) m = fmaxf(m, base[p * G]);
    maxpU[i] = m;
  }
}

// K4/K11: activation outputs of a hidden layer  (3694592 threads)
__global__ void k_slayer(const float* __restrict__ U, const float* __restrict__ V,
                         const float* __restrict__ maxeV, const float* __restrict__ maxpU,
                         float* __restrict__ s110, float* __restrict__ s011,
                         float* __restrict__ s001) {
  int t = blockIdx.x * 256 + threadIdx.x;
  if (t < B * N * P * G) {             // s110 = lrelu(U + maxeV[b,n,g])
    int g = t & 127; int bnp = t >> 7; int bn = bnp >> 4;
    s110[t] = lrelu(U[t] + maxeV[bn * G + g]);
  } else if (t < B * N * P * G + B * N * G * E) {  // s011 = lrelu(maxpU + V)
    int i = t - B * N * P * G;
    int r = i / 96;                    // r = (b*N+n)*G+g
    s011[i] = lrelu(maxpU[r] + V[i]);
  } else {                             // s001[b,n,e] = max_g lrelu(maxpU + V)
    int i = t - (B * N * P * G + B * N * G * E);
    int e = i % 96; int bn = i / 96;
    float m = -INFINITY;
    for (int g = 0; g < G; g++)
      m = fmaxf(m, maxpU[bn * G + g] + V[((size_t)bn * G + g) * E + e]);
    s001[i] = lrelu(m);
  }
}

// K5: layer-1 input reductions  (94208 threads)
__global__ void k_reduce1(const float* __restrict__ s110, const float* __restrict__ s011,
                          float* __restrict__ mp110, float* __restrict__ mg110,
                          float* __restrict__ mg011, float* __restrict__ me011) {
  int t = blockIdx.x * 256 + threadIdx.x;
  if (t < 32768) {                     // mp110[b,c,g] = max_p s110 ; t=(b*N+c)*G+g
    int g = t & 127; int bc = t >> 7;
    const float* base = s110 + ((size_t)bc * P) * G + g;
    float m = -INFINITY;
    for (int p = 0; p < P; p++) m = fmaxf(m, base[p * G]);
    mp110[t] = m;
  } else if (t < 36864) {              // mg110[b,c,p] = max_g s110
    int i = t - 32768;
    const float* base = s110 + (size_t)i * G;
    float m = -INFINITY;
    for (int g = 0; g < G; g++) m = fmaxf(m, base[g]);
    mg110[i] = m;
  } else if (t < 61440) {              // mg011[b,c,e] = max_g s011
    int i = t - 36864;
    int e = i % 96; int bc = i / 96;
    const float* base = s011 + ((size_t)bc * G) * E + e;
    float m = -INFINITY;
    for (int g = 0; g < G; g++) m = fmaxf(m, base[g * E]);
    mg011[i] = m;
  } else if (t < 94208) {              // me011[b,c,g] = max_e s011 ; i=(b*N+c)*G+g
    int i = t - 61440;
    const float* base = s011 + (size_t)i * E;
    float m = -INFINITY;
    for (int e = 0; e < E; e++) m = fmaxf(m, base[e]);
    me011[i] = m;
  }
}

// K6: small per-axis GEMMs for layer 1  (61440 threads)
__global__ void k_sg(const float* __restrict__ W1, const float* __restrict__ mp110,
                     const float* __restrict__ mg110, const float* __restrict__ mg011,
                     const float* __restrict__ me011, const float* __restrict__ s001,
                     float* __restrict__ C1p, float* __restrict__ BF1g,
                     float* __restrict__ EG1e) {
  int t = blockIdx.x * 256 + threadIdx.x;
  if (t < 4096) {                      // C1p[b,n,p] = W1[2] @ mg110
    int p = t & 15, n = (t >> 4) & 127, b = t >> 11;
    float acc = 0.f;
    for (int c = 0; c < N; c++)
      acc += W1[(2 * N + n) * N + c] * mg110[(b * N + c) * P + p];
    C1p[t] = acc;
  } else if (t < 36864) {              // BF1g[b,n,g] = W1[1]@mp110 + W1[5]@me011
    int i = t - 4096;
    int g = i & 127, n = (i >> 7) & 127, b = i >> 14;
    float acc = 0.f;
    for (int c = 0; c < N; c++) {
      acc += W1[(1 * N + n) * N + c] * mp110[(b * N + c) * G + g];
      acc += W1[(5 * N + n) * N + c] * me011[(b * N + c) * G + g];
    }
    BF1g[i] = acc;
  } else {                             // EG1e[b,n,e] = W1[4]@mg011 + W1[6]@s001
    int i = t - 36864;
    int e = i % 96; int r = i / 96; int n = r & 127, b = r >> 7;
    float acc = 0.f;
    for (int c = 0; c < N; c++) {
      acc += W1[(4 * N + n) * N + c] * mg011[(b * N + c) * E + e];
      acc += W1[(6 * N + n) * N + c] * s001[(b * N + c) * E + e];
    }
    EG1e[i] = acc;
  }
}

// K7: U1[b,n,p,g] = W1[0] @ s110_1 + C1p + BF1g + bias   (131072 threads, 4 g each)
__global__ void k_U1(const float* __restrict__ s110, const float* __restrict__ W1,
                     const float* __restrict__ b1, const float* __restrict__ C1p,
                     const float* __restrict__ BF1g, float* __restrict__ U) {
  int t = blockIdx.x * 256 + threadIdx.x;
  int g4 = t & 31, p = (t >> 5) & 15, n = (t >> 9) & 127, b = t >> 16;
  int g = g4 * 4;
  const float* wrow = W1 + (size_t)n * N;
  const float* in = s110 + (size_t)b * N * P * G + p * G + g;
  float a0 = 0, a1 = 0, a2 = 0, a3 = 0;
  for (int c = 0; c < N; c++) {
    float4 v = *(const float4*)(in + (size_t)c * P * G);
    float wc = wrow[c];
    a0 += wc * v.x; a1 += wc * v.y; a2 += wc * v.z; a3 += wc * v.w;
  }
  float base = b1[n] + b1[N + n] + b1[2 * N + n] + b1[5 * N + n]
             + C1p[(b * N + n) * P + p];
  const float* bf = BF1g + (b * N + n) * G + g;
  float4 outv = make_float4(a0 + base + bf[0], a1 + base + bf[1],
                            a2 + base + bf[2], a3 + base + bf[3]);
  *(float4*)&U[((size_t)(b * N + n) * P + p) * G + g] = outv;
}

// K8: V1[b,n,g,e] = W1[3] @ s011_1 + EG1e + bias.  LDS-tiled per (b,g).
__global__ void __launch_bounds__(256) k_V1(const float* __restrict__ s011,
                                            const float* __restrict__ W1,
                                            const float* __restrict__ b1,
                                            const float* __restrict__ EG1e,
                                            float* __restrict__ V) {
  __shared__ float lds[N * E];  // 48 KiB: s011_1[b, :, g, :]
  const int blk = blockIdx.x;
  const int g = blk & (G - 1);
  const int b = blk >> 7;
  const float* src = s011 + ((size_t)(b * N * G) + g) * E;
  for (int idx4 = threadIdx.x; idx4 < N * E / 4; idx4 += 256) {
    int c = idx4 / (E / 4), e4 = idx4 - c * (E / 4);
    *(float4*)&lds[c * E + e4 * 4] = *(const float4*)&src[(size_t)c * G * E + e4 * 4];
  }
  __syncthreads();
  for (int j = threadIdx.x; j < (N / 4) * (E / 4); j += 256) {
    const int e4 = j % (E / 4);
    const int n4 = j / (E / 4);
    const int e = e4 * 4, n = n4 * 4;
    float acc[4][4];
#pragma unroll
    for (int ni = 0; ni < 4; ni++) {
      float bv = b1[3 * N + n + ni] + b1[4 * N + n + ni] + b1[6 * N + n + ni];
      const float* eg = EG1e + (b * N + n + ni) * E + e;
#pragma unroll
      for (int ei = 0; ei < 4; ei++) acc[ni][ei] = bv + eg[ei];
    }
    const float* w0 = W1 + (size_t)(3 * N + n) * N;
    for (int c = 0; c < N; c += 4) {
      float4 v0 = *(const float4*)&lds[c * E + e];
      float4 v1 = *(const float4*)&lds[(c + 1) * E + e];
      float4 v2 = *(const float4*)&lds[(c + 2) * E + e];
      float4 v3 = *(const float4*)&lds[(c + 3) * E + e];
#pragma unroll
      for (int ni = 0; ni < 4; ni++) {
        float4 wv = *(const float4*)&w0[ni * N + c];
        acc[ni][0] += wv.x * v0.x + wv.y * v1.x + wv.z * v2.x + wv.w * v3.x;
        acc[ni][1] += wv.x * v0.y + wv.y * v1.y + wv.z * v2.y + wv.w * v3.y;
        acc[ni][2] += wv.x * v0.z + wv.y * v1.z + wv.z * v2.z + wv.w * v3.z;
        acc[ni][3] += wv.x * v0.w + wv.y * v1.w + wv.z * v2.w + wv.w * v3.w;
      }
    }
#pragma unroll
    for (int ni = 0; ni < 4; ni++) {
      float4 outv = make_float4(acc[ni][0], acc[ni][1], acc[ni][2], acc[ni][3]);
      *(float4*)&V[((size_t)(b * N + n + ni) * G + g) * E + e] = outv;
    }
  }
}

// K12: head means: m110[b,n,p]=mean_g s110_2 ; m011e[b,n,e]=mean_g s011_2
__global__ void k_means(const float* __restrict__ s110, const float* __restrict__ s011,
                        float* __restrict__ m110, float* __restrict__ m011e) {
  int t = blockIdx.x * 256 + threadIdx.x;
  if (t < 4096) {
    const float* base = s110 + (size_t)t * G;
    float s = 0.f;
    for (int g = 0; g < G; g++) s += base[g];
    m110[t] = s * (1.f / G);
  } else if (t < 28672) {
    int i = t - 4096;
    int e = i % 96; int bn = i / 96;
    const float* base = s011 + ((size_t)bn * G) * E + e;
    float s = 0.f;
    for (int g = 0; g < G; g++) s += base[g * E];
    m011e[i] = s * (1.f / G);
  }
}

// K13: heads. one block per (b,o), 128 threads.
__global__ void __launch_bounds__(128) k_final(const float* __restrict__ m110,
                                               const float* __restrict__ m011e,
                                               const float* __restrict__ s001,
                                               const float* __restrict__ Wact,
                                               const float* __restrict__ bact,
                                               const float* __restrict__ Wcrit,
                                               const float* __restrict__ bcrit,
                                               float* __restrict__ out) {
  __shared__ float sm011[N], sm001[N], scp[P], sce[E], srow[P], scol[E];
  const int bo = blockIdx.x;
  const int o = bo & 1, b = bo >> 1;
  const int t = threadIdx.x;
  {  // per-n means over e
    float s1 = 0.f, s2 = 0.f;
    const float* p1 = m011e + (b * N + t) * E;
    const float* p2 = s001 + (b * N + t) * E;
    for (int e = 0; e < E; e++) { s1 += p1[e]; s2 += p2[e]; }
    sm011[t] = s1 * (1.f / E);
    sm001[t] = s2 * (1.f / E);
  }
  __syncthreads();
  if (t < P) {
    const float* wa0 = Wact + o * N;
    const float* wa1 = Wact + (1 * CO + o) * N;
    const float* wa2 = Wact + (2 * CO + o) * N;
    const float* wc0 = Wcrit + o * N;
    float a = 0.f, c = 0.f, aa = 0.f;
    for (int n = 0; n < N; n++) {
      float m = m110[(b * N + n) * P + t];
      a += wa0[n] * m;
      c += wc0[n] * m;
      aa += wa1[n] * sm011[n] + wa2[n] * sm001[n];
    }
    float act = a + aa + bact[o] + bact[CO + o] + bact[2 * CO + o];
    out[(b * CO + o) * P + t] = lrelu(act);
    scp[t] = c + bcrit[o];
  } else if (t < P + E) {
    int e = t - P;
    const float* wc1 = Wcrit + (1 * CO + o) * N;
    const float* wc2 = Wcrit + (2 * CO + o) * N;
    float c = 0.f;
    for (int n = 0; n < N; n++)
      c += wc1[n] * m011e[(b * N + n) * E + e] + wc2[n] * s001[(b * N + n) * E + e];
    sce[e] = c + bcrit[CO + o] + bcrit[2 * CO + o];
  }
  __syncthreads();
  if (t < P) {
    float m = -INFINITY;
    for (int e = 0; e < E; e++) m = fmaxf(m, lrelu(scp[t] + sce[e]));
    srow[t] = m;
  } else if (t < P + E) {
    int e = t - P;
    float m = -INFINITY;
    for (int p = 0; p < P; p++) m = fmaxf(m, lrelu(scp[p] + sce[e]));
    scol[e] = m;
  }
  __syncthreads();
  if (t == 0) {
    float v110 = 0.f, v011 = 0.f;
    for (int p = 0; p < P; p++) v110 += srow[p];
    for (int e = 0; e < E; e++) v011 += scol[e];
    out[B * CO * P + b * CO + o] = 2.f + v110 + 2.f * v011;
  }
}

extern "C" void kernel_launch(void* const* d_in, const int* in_sizes, int n_in,
                              void* d_out, int out_size, void* d_ws, size_t ws_size,
                              hipStream_t stream) {
  const float* x110   = (const float*)d_in[0];
  const float* x011   = (const float*)d_in[1];
  const float* x001   = (const float*)d_in[2];
  const float* W0_110 = (const float*)d_in[3];
  const float* b0_110 = (const float*)d_in[4];
  const float* W0_011 = (const float*)d_in[5];
  const float* b0_011 = (const float*)d_in[6];
  const float* W0_001 = (const float*)d_in[7];
  const float* b0_001 = (const float*)d_in[8];
  const float* W1     = (const float*)d_in[9];
  const float* b1     = (const float*)d_in[10];
  const float* Wact   = (const float*)d_in[11];
  const float* bact   = (const float*)d_in[12];
  const float* Wcrit  = (const float*)d_in[13];
  const float* bcrit  = (const float*)d_in[14];
  float* out = (float*)d_out;
  float* w = (float*)d_ws;

  float* U      = w + OFF_U;
  float* V      = w + OFF_V;
  float* s110   = w + OFF_S110;
  float* s011   = w + OFF_S011;
  float* s001   = w + OFF_S001;
  float* maxeV  = w + OFF_MAXEV;
  float* maxpU  = w + OFF_MAXPU;
  float* rmp110 = w + OFF_RMP110;
  float* rmg110 = w + OFF_RMG110;
  float* rme011 = w + OFF_RME011;
  float* rmg011 = w + OFF_RMG011;
  float* mp110  = w + OFF_MP110;
  float* mg110  = w + OFF_MG110;
  float* mg011  = w + OFF_MG011;
  float* me011  = w + OFF_ME011;
  float* C1p    = w + OFF_C1P;
  float* BF1g   = w + OFF_BF1G;
  float* EG1e   = w + OFF_EG1E;
  float* m110   = w + OFF_M110;
  float* m011e  = w + OFF_M011E;

  // ---- layer 0 ----
  k_in_reduce<<<8, 256, 0, stream>>>(x110, x011, rmp110, rmg110, rme011, rmg011);
  k_U0<<<2048, 256, 0, stream>>>(x110, W0_110, b0_110, W0_011, b0_011,
                                 rmp110, rmg110, rme011, U);
  k_V0<<<12288, 256, 0, stream>>>(x011, x001, W0_011, b0_011, W0_001, b0_001,
                                  rmg011, V);
  k_max<<<256, 256, 0, stream>>>(U, V, maxeV, maxpU);
  k_slayer<<<14432, 256, 0, stream>>>(U, V, maxeV, maxpU, s110, s011, s001);
  // ---- layer 1 ----
  k_reduce1<<<368, 256, 0, stream>>>(s110, s011, mp110, mg110, mg011, me011);
  k_sg<<<240, 256, 0, stream>>>(W1, mp110, mg110, mg011, me011, s001,
                                C1p, BF1g, EG1e);
  k_U1<<<512, 256, 0, stream>>>(s110, W1, b1, C1p, BF1g, U);
  k_V1<<<256, 256, 0, stream>>>(s011, W1, b1, EG1e, V);
  k_max<<<256, 256, 0, stream>>>(U, V, maxeV, maxpU);
  k_slayer<<<14432, 256, 0, stream>>>(U, V, maxeV, maxpU, s110, s011, s001);
  // ---- heads ----
  k_means<<<112, 256, 0, stream>>>(s110, s011, m110, m011e);
  k_final<<<4, 128, 0, stream>>>(m110, m011e, s001, Wact, bact, Wcrit, bcrit, out);
}

// Round 2
// 125.665 us; speedup vs baseline: 1.8139x; 1.8139x over previous
//
#include <hip/hip_runtime.h>
#include <math.h>

#define DEVI __device__ __forceinline__

constexpr int B = 2, P = 16, G = 128, E = 96, N = 128, CO = 2;

DEVI float lrelu(float x) { return x > 0.f ? x : 0.01f * x; }
DEVI float4 lrelu4(float4 v) {
  return make_float4(lrelu(v.x), lrelu(v.y), lrelu(v.z), lrelu(v.w));
}

// ---- workspace layout (floats) ----
constexpr int OFF_U0     = 0;                        // B*N*P*G = 524288
constexpr int OFF_V0     = OFF_U0 + 524288;          // B*N*G*E = 3145728
constexpr int OFF_S110   = OFF_V0 + 3145728;         // 524288
constexpr int OFF_MAXPU0 = OFF_S110 + 524288;        // B*N*G = 32768
constexpr int OFF_MP110  = OFF_MAXPU0 + 32768;       // 32768 (== me011)
constexpr int OFF_MG110  = OFF_MP110 + 32768;        // B*N*P = 4096
constexpr int OFF_S001A  = OFF_MG110 + 4096;         // B*N*E = 24576 (== mg011)
constexpr int OFF_C1P    = OFF_S001A + 24576;        // 4096
constexpr int OFF_BF1G   = OFF_C1P + 4096;           // 32768
constexpr int OFF_EG1E   = OFF_BF1G + 32768;         // 24576
constexpr int OFF_U1     = OFF_EG1E + 24576;         // 524288
constexpr int OFF_V1     = OFF_U1 + 524288;          // 3145728
constexpr int OFF_M110   = OFF_V1 + 3145728;         // 4096
constexpr int OFF_M011E  = OFF_M110 + 4096;          // 24576
constexpr int OFF_S001B  = OFF_M011E + 24576;        // 24576

// ---------------------------------------------------------------------------
// K0: tiny input reductions
__global__ void k_in_reduce(const float* __restrict__ x110,
                            const float* __restrict__ x011,
                            float* __restrict__ rmp110, float* __restrict__ rmg110,
                            float* __restrict__ rme011, float* __restrict__ rmg011) {
  int t = blockIdx.x * 256 + threadIdx.x;
  if (t < 1024) {                      // rmp110[b,c,g] = max_p x110
    int g = t & 127, c = (t >> 7) & 3, b = t >> 9;
    const float* base = x110 + ((b * 4 + c) * P) * G + g;
    float m = -INFINITY;
    for (int p = 0; p < P; p++) m = fmaxf(m, base[p * G]);
    rmp110[t] = m;
  } else if (t < 1152) {               // rmg110[b,c,p] = max_g x110
    int i = t - 1024;
    int p = i & 15, c = (i >> 4) & 3, b = i >> 6;
    const float* base = x110 + ((b * 4 + c) * P + p) * G;
    float m = -INFINITY;
    for (int g = 0; g < G; g++) m = fmaxf(m, base[g]);
    rmg110[i] = m;
  } else if (t < 1664) {               // rme011[b,c,g] = max_e x011
    int i = t - 1152;
    int g = i & 127, c = (i >> 7) & 1, b = i >> 8;
    const float* base = x011 + ((b * 2 + c) * G + g) * E;
    float m = -INFINITY;
    for (int e = 0; e < E; e++) m = fmaxf(m, base[e]);
    rme011[i] = m;
  } else if (t < 2048) {               // rmg011[b,c,e] = max_g x011
    int i = t - 1664;
    int e = i % 96; int r = i / 96; int c = r & 1, b = r >> 1;
    const float* base = x011 + ((b * 2 + c) * G) * E + e;
    float m = -INFINITY;
    for (int g = 0; g < G; g++) m = fmaxf(m, base[g * E]);
    rmg011[i] = m;
  }
}

// K1: U0 (blocks 0..2047) + V0 (blocks 2048..14335) merged
__global__ void k_UV0(const float* __restrict__ x110, const float* __restrict__ x011,
                      const float* __restrict__ x001,
                      const float* __restrict__ W0_110, const float* __restrict__ b0_110,
                      const float* __restrict__ W0_011, const float* __restrict__ b0_011,
                      const float* __restrict__ W0_001, const float* __restrict__ b0_001,
                      const float* __restrict__ rmp110, const float* __restrict__ rmg110,
                      const float* __restrict__ rme011, const float* __restrict__ rmg011,
                      float* __restrict__ U, float* __restrict__ V) {
  int blk = blockIdx.x;
  if (blk < 2048) {                    // U0[b,n,p,g]
    int t = blk * 256 + threadIdx.x;
    int g = t & 127, p = (t >> 7) & 15, n = (t >> 11) & 127, b = t >> 18;
    float acc = b0_110[n] + b0_110[N + n] + b0_110[2 * N + n] + b0_011[2 * N + n];
#pragma unroll
    for (int c = 0; c < 4; c++) {
      acc += W0_110[n * 4 + c]           * x110[((b * 4 + c) * P + p) * G + g];
      acc += W0_110[(N + n) * 4 + c]     * rmp110[(b * 4 + c) * G + g];
      acc += W0_110[(2 * N + n) * 4 + c] * rmg110[(b * 4 + c) * P + p];
    }
#pragma unroll
    for (int c = 0; c < 2; c++)
      acc += W0_011[(2 * N + n) * 2 + c] * rme011[(b * 2 + c) * G + g];
    U[t] = acc;
  } else {                             // V0[b,n,g,e]
    int t = (blk - 2048) * 256 + threadIdx.x;
    int e = t % 96; int r = t / 96;
    int g = r & 127, n = (r >> 7) & 127, b = r >> 14;
    float acc = b0_011[n] + b0_011[N + n] + b0_001[n];
#pragma unroll
    for (int c = 0; c < 2; c++) {
      acc += W0_011[n * 2 + c]       * x011[((b * 2 + c) * G + g) * E + e];
      acc += W0_011[(N + n) * 2 + c] * rmg011[(b * 2 + c) * E + e];
    }
    acc += W0_001[n] * x001[b * E + e];
    V[t] = acc;
  }
}

// K2: per-(b,n) post-processing of layer 0.
// Writes s110_1, maxpU0, mp110(=me011), mg110, s001a(=mg011).
__global__ void __launch_bounds__(256) k_post0(
    const float* __restrict__ U, const float* __restrict__ V,
    float* __restrict__ s110, float* __restrict__ maxpU0,
    float* __restrict__ mp110, float* __restrict__ mg110,
    float* __restrict__ s001a) {
  __shared__ float uU[P * G];          // 8 KiB
  __shared__ float part[256];
  __shared__ float smaxeV[G], smaxpU[G];
  const int bn = blockIdx.x;
  const int tid = threadIdx.x;
  // load U row (2048 floats)
  const float4* usrc = (const float4*)(U + (size_t)bn * P * G);
  float4* udst = (float4*)uU;
  udst[tid] = usrc[tid];
  udst[tid + 256] = usrc[tid + 256];
  // maxeV partials: thread (g, half) reads 48 contiguous floats of V row
  {
    int g = tid & 127, h = tid >> 7;
    const float* vrow = V + ((size_t)bn * G + g) * E + h * 48;
    float m = -INFINITY;
#pragma unroll
    for (int j = 0; j < 12; j++) {
      float4 v = *(const float4*)(vrow + j * 4);
      m = fmaxf(m, fmaxf(fmaxf(v.x, v.y), fmaxf(v.z, v.w)));
    }
    part[tid] = m;
  }
  __syncthreads();
  if (tid < G) {
    smaxeV[tid] = fmaxf(part[tid], part[tid + 128]);
    float mp = -INFINITY;
    for (int p = 0; p < P; p++) mp = fmaxf(mp, uU[p * G + tid]);
    smaxpU[tid] = mp;
    maxpU0[bn * G + tid] = mp;
  }
  __syncthreads();
  // s110_1 = lrelu(U + maxeV[g])
  {
    float4* sdst = (float4*)(s110 + (size_t)bn * P * G);
#pragma unroll
    for (int k = 0; k < 2; k++) {
      int i = tid + k * 256;
      int g4 = i & 31;
      float4 u = ((float4*)uU)[i];
      float4 mv = *(float4*)&smaxeV[g4 * 4];
      sdst[i] = make_float4(lrelu(u.x + mv.x), lrelu(u.y + mv.y),
                            lrelu(u.z + mv.z), lrelu(u.w + mv.w));
    }
  }
  if (tid < G)   // mp110 == me011 == lrelu(maxpU + maxeV)
    mp110[bn * G + tid] = lrelu(smaxpU[tid] + smaxeV[tid]);
  if (tid < P) { // mg110[p] = lrelu(max_g(U[p,g]+maxeV[g]))
    float mm = -INFINITY;
    for (int g = 0; g < G; g++) mm = fmaxf(mm, uU[tid * G + g] + smaxeV[g]);
    mg110[bn * P + tid] = lrelu(mm);
  }
  if (tid < E) { // s001a == mg011 == lrelu(max_g(maxpU[g]+V[g,e]))
    float mm = -INFINITY;
    const float* vcol = V + (size_t)bn * G * E + tid;
    for (int g = 0; g < G; g++) mm = fmaxf(mm, smaxpU[g] + vcol[g * E]);
    s001a[bn * E + tid] = lrelu(mm);
  }
}

// K3: small per-axis GEMMs for layer 1 (weights folded via identities)
__global__ void k_sg(const float* __restrict__ W1, const float* __restrict__ mp110,
                     const float* __restrict__ mg110, const float* __restrict__ s001a,
                     float* __restrict__ C1p, float* __restrict__ BF1g,
                     float* __restrict__ EG1e) {
  int t = blockIdx.x * 256 + threadIdx.x;
  if (t < 4096) {                      // C1p = W1[2] @ mg110
    int p = t & 15, n = (t >> 4) & 127, b = t >> 11;
    float acc = 0.f;
    for (int c = 0; c < N; c++)
      acc += W1[(2 * N + n) * N + c] * mg110[(b * N + c) * P + p];
    C1p[t] = acc;
  } else if (t < 36864) {              // BF1g = (W1[1]+W1[5]) @ mp110
    int i = t - 4096;
    int g = i & 127, n = (i >> 7) & 127, b = i >> 14;
    float acc = 0.f;
    for (int c = 0; c < N; c++)
      acc += (W1[(1 * N + n) * N + c] + W1[(5 * N + n) * N + c])
             * mp110[(b * N + c) * G + g];
    BF1g[i] = acc;
  } else {                             // EG1e = (W1[4]+W1[6]) @ s001a
    int i = t - 36864;
    int e = i % 96; int r = i / 96; int n = r & 127, b = r >> 7;
    float acc = 0.f;
    for (int c = 0; c < N; c++)
      acc += (W1[(4 * N + n) * N + c] + W1[(6 * N + n) * N + c])
             * s001a[(b * N + c) * E + e];
    EG1e[i] = acc;
  }
}

// K4: V1 (blocks 0..255, per (b,g), s011 staged inline) + U1 (blocks 256..383)
__global__ void __launch_bounds__(256) k_V1U1(
    const float* __restrict__ V0, const float* __restrict__ maxpU0,
    const float* __restrict__ s110, const float* __restrict__ W1,
    const float* __restrict__ b1, const float* __restrict__ C1p,
    const float* __restrict__ BF1g, const float* __restrict__ EG1e,
    float* __restrict__ U1, float* __restrict__ V1) {
  __shared__ float sS[N * E];          // 48 KiB (V path only)
  const int blk = blockIdx.x;
  const int tid = threadIdx.x;
  if (blk < 256) {
    // ---- V1[b,n,g,e] = W1[3] @ lrelu(maxpU0 + V0) + EG1e + bias ----
    const int g = blk & 127, b = blk >> 7;
    for (int i4 = tid; i4 < N * E / 4; i4 += 256) {
      int c = i4 / 24, e4 = i4 - c * 24;
      float4 v = *(const float4*)(V0 + ((size_t)(b * N + c) * G + g) * E + e4 * 4);
      float mp = maxpU0[(b * N + c) * G + g];
      *(float4*)&sS[c * E + e4 * 4] =
          make_float4(lrelu(v.x + mp), lrelu(v.y + mp),
                      lrelu(v.z + mp), lrelu(v.w + mp));
    }
    __syncthreads();
    const int e12 = tid & 7, n4 = tid >> 3;   // 8 e-groups x 32 n-groups
    const int n0 = n4 * 4, e0 = e12 * 12;
    float4 acc[4][3];
#pragma unroll
    for (int ni = 0; ni < 4; ni++) {
      int n = n0 + ni;
      float bb = b1[3 * N + n] + b1[4 * N + n] + b1[6 * N + n];
      const float* eg = EG1e + (b * N + n) * E + e0;
#pragma unroll
      for (int k = 0; k < 3; k++)
        acc[ni][k] = make_float4(bb + eg[k * 4], bb + eg[k * 4 + 1],
                                 bb + eg[k * 4 + 2], bb + eg[k * 4 + 3]);
    }
    for (int c = 0; c < N; c += 4) {
      float4 wv[4];
#pragma unroll
      for (int ni = 0; ni < 4; ni++)
        wv[ni] = *(const float4*)&W1[(size_t)(3 * N + n0 + ni) * N + c];
#pragma unroll
      for (int cc = 0; cc < 4; cc++) {
        float4 s0 = *(float4*)&sS[(c + cc) * E + e0];
        float4 s1 = *(float4*)&sS[(c + cc) * E + e0 + 4];
        float4 s2 = *(float4*)&sS[(c + cc) * E + e0 + 8];
#pragma unroll
        for (int ni = 0; ni < 4; ni++) {
          float wc = cc == 0 ? wv[ni].x : cc == 1 ? wv[ni].y : cc == 2 ? wv[ni].z : wv[ni].w;
          acc[ni][0].x += wc * s0.x; acc[ni][0].y += wc * s0.y;
          acc[ni][0].z += wc * s0.z; acc[ni][0].w += wc * s0.w;
          acc[ni][1].x += wc * s1.x; acc[ni][1].y += wc * s1.y;
          acc[ni][1].z += wc * s1.z; acc[ni][1].w += wc * s1.w;
          acc[ni][2].x += wc * s2.x; acc[ni][2].y += wc * s2.y;
          acc[ni][2].z += wc * s2.z; acc[ni][2].w += wc * s2.w;
        }
      }
    }
#pragma unroll
    for (int ni = 0; ni < 4; ni++) {
      float* dst = V1 + ((size_t)(b * N + n0 + ni) * G + g) * E + e0;
#pragma unroll
      for (int k = 0; k < 3; k++) *(float4*)(dst + k * 4) = acc[ni][k];
    }
  } else {
    // ---- U1[b,n,p,g] = W1[0] @ s110_1 + C1p + BF1g + bias, 4n x 4g per thread
    int t = (blk - 256) * 256 + tid;   // < 32768
    int g4 = t & 31, p = (t >> 5) & 15, n4 = (t >> 9) & 31, b = t >> 14;
    int n0 = n4 * 4;
    float4 a[4];
#pragma unroll
    for (int ni = 0; ni < 4; ni++) {
      int n = n0 + ni;
      float bb = b1[n] + b1[N + n] + b1[2 * N + n] + b1[5 * N + n]
               + C1p[(b * N + n) * P + p];
      float4 bf = *(const float4*)&BF1g[(b * N + n) * G + g4 * 4];
      a[ni] = make_float4(bb + bf.x, bb + bf.y, bb + bf.z, bb + bf.w);
    }
#pragma unroll 4
    for (int c = 0; c < N; c++) {
      float4 v = *(const float4*)&s110[((size_t)(b * N + c) * P + p) * G + g4 * 4];
#pragma unroll
      for (int ni = 0; ni < 4; ni++) {
        float wc = W1[(size_t)(n0 + ni) * N + c];
        a[ni].x += wc * v.x; a[ni].y += wc * v.y;
        a[ni].z += wc * v.z; a[ni].w += wc * v.w;
      }
    }
#pragma unroll
    for (int ni = 0; ni < 4; ni++)
      *(float4*)&U1[((size_t)(b * N + n0 + ni) * P + p) * G + g4 * 4] = a[ni];
  }
}

// K5: per-(b,n) reduction of layer-2 tiles straight to head inputs.
__global__ void __launch_bounds__(256) k_post1(
    const float* __restrict__ U1, const float* __restrict__ V1,
    float* __restrict__ m110, float* __restrict__ m011e,
    float* __restrict__ s001b) {
  __shared__ float uU[P * G];
  __shared__ float part[256];
  __shared__ float smaxeV[G], smaxpU[G];
  const int bn = blockIdx.x;
  const int tid = threadIdx.x;
  const float4* usrc = (const float4*)(U1 + (size_t)bn * P * G);
  float4* udst = (float4*)uU;
  udst[tid] = usrc[tid];
  udst[tid + 256] = usrc[tid + 256];
  {
    int g = tid & 127, h = tid >> 7;
    const float* vrow = V1 + ((size_t)bn * G + g) * E + h * 48;
    float m = -INFINITY;
#pragma unroll
    for (int j = 0; j < 12; j++) {
      float4 v = *(const float4*)(vrow + j * 4);
      m = fmaxf(m, fmaxf(fmaxf(v.x, v.y), fmaxf(v.z, v.w)));
    }
    part[tid] = m;
  }
  __syncthreads();
  if (tid < G) {
    smaxeV[tid] = fmaxf(part[tid], part[tid + 128]);
    float mp = -INFINITY;
    for (int p = 0; p < P; p++) mp = fmaxf(mp, uU[p * G + tid]);
    smaxpU[tid] = mp;
  }
  __syncthreads();
  if (tid < P) {   // m110[p] = mean_g lrelu(U1[p,g] + maxeV1[g])
    float s = 0.f;
    for (int g = 0; g < G; g++) s += lrelu(uU[tid * G + g] + smaxeV[g]);
    m110[bn * P + tid] = s * (1.f / G);
  }
  if (tid < E) {   // m011e = mean_g lrelu(maxpU1+V1) ; s001b = lrelu(max_g(...))
    float s = 0.f, mm = -INFINITY;
    const float* vcol = V1 + (size_t)bn * G * E + tid;
    for (int g = 0; g < G; g++) {
      float pre = smaxpU[g] + vcol[g * E];
      s += lrelu(pre);
      mm = fmaxf(mm, pre);
    }
    m011e[bn * E + tid] = s * (1.f / G);
    s001b[bn * E + tid] = lrelu(mm);
  }
}

// K6: heads. one block per (b,o), 128 threads.
__global__ void __launch_bounds__(128) k_final(const float* __restrict__ m110,
                                               const float* __restrict__ m011e,
                                               const float* __restrict__ s001,
                                               const float* __restrict__ Wact,
                                               const float* __restrict__ bact,
                                               const float* __restrict__ Wcrit,
                                               const float* __restrict__ bcrit,
                                               float* __restrict__ out) {
  __shared__ float sm011[N], sm001[N], scp[P], sce[E], srow[P], scol[E];
  const int bo = blockIdx.x;
  const int o = bo & 1, b = bo >> 1;
  const int t = threadIdx.x;
  {
    float s1 = 0.f, s2 = 0.f;
    const float* p1 = m011e + (b * N + t) * E;
    const float* p2 = s001 + (b * N + t) * E;
    for (int e = 0; e < E; e++) { s1 += p1[e]; s2 += p2[e]; }
    sm011[t] = s1 * (1.f / E);
    sm001[t] = s2 * (1.f / E);
  }
  __syncthreads();
  if (t < P) {
    const float* wa0 = Wact + o * N;
    const float* wa1 = Wact + (1 * CO + o) * N;
    const float* wa2 = Wact + (2 * CO + o) * N;
    const float* wc0 = Wcrit + o * N;
    float a = 0.f, c = 0.f, aa = 0.f;
    for (int n = 0; n < N; n++) {
      float m = m110[(b * N + n) * P + t];
      a += wa0[n] * m;
      c += wc0[n] * m;
      aa += wa1[n] * sm011[n] + wa2[n] * sm001[n];
    }
    float act = a + aa + bact[o] + bact[CO + o] + bact[2 * CO + o];
    out[(b * CO + o) * P + t] = lrelu(act);
    scp[t] = c + bcrit[o];
  } else if (t < P + E) {
    int e = t - P;
    const float* wc1 = Wcrit + (1 * CO + o) * N;
    const float* wc2 = Wcrit + (2 * CO + o) * N;
    float c = 0.f;
    for (int n = 0; n < N; n++)
      c += wc1[n] * m011e[(b * N + n) * E + e] + wc2[n] * s001[(b * N + n) * E + e];
    sce[e] = c + bcrit[CO + o] + bcrit[2 * CO + o];
  }
  __syncthreads();
  if (t < P) {
    float m = -INFINITY;
    for (int e = 0; e < E; e++) m = fmaxf(m, lrelu(scp[t] + sce[e]));
    srow[t] = m;
  } else if (t < P + E) {
    int e = t - P;
    float m = -INFINITY;
    for (int p = 0; p < P; p++) m = fmaxf(m, lrelu(scp[p] + sce[e]));
    scol[e] = m;
  }
  __syncthreads();
  if (t == 0) {
    float v110 = 0.f, v011 = 0.f;
    for (int p = 0; p < P; p++) v110 += srow[p];
    for (int e = 0; e < E; e++) v011 += scol[e];
    out[B * CO * P + b * CO + o] = 2.f + v110 + 2.f * v011;
  }
}

extern "C" void kernel_launch(void* const* d_in, const int* in_sizes, int n_in,
                              void* d_out, int out_size, void* d_ws, size_t ws_size,
                              hipStream_t stream) {
  const float* x110   = (const float*)d_in[0];
  const float* x011   = (const float*)d_in[1];
  const float* x001   = (const float*)d_in[2];
  const float* W0_110 = (const float*)d_in[3];
  const float* b0_110 = (const float*)d_in[4];
  const float* W0_011 = (const float*)d_in[5];
  const float* b0_011 = (const float*)d_in[6];
  const float* W0_001 = (const float*)d_in[7];
  const float* b0_001 = (const float*)d_in[8];
  const float* W1     = (const float*)d_in[9];
  const float* b1     = (const float*)d_in[10];
  const float* Wact   = (const float*)d_in[11];
  const float* bact   = (const float*)d_in[12];
  const float* Wcrit  = (const float*)d_in[13];
  const float* bcrit  = (const float*)d_in[14];
  float* out = (float*)d_out;
  float* w = (float*)d_ws;

  float* U0     = w + OFF_U0;
  float* V0     = w + OFF_V0;
  float* s110   = w + OFF_S110;
  float* maxpU0 = w + OFF_MAXPU0;
  float* mp110  = w + OFF_MP110;
  float* mg110  = w + OFF_MG110;
  float* s001a  = w + OFF_S001A;
  float* C1p    = w + OFF_C1P;
  float* BF1g   = w + OFF_BF1G;
  float* EG1e   = w + OFF_EG1E;
  float* U1     = w + OFF_U1;
  float* V1     = w + OFF_V1;
  float* m110   = w + OFF_M110;
  float* m011e  = w + OFF_M011E;
  float* s001b  = w + OFF_S001B;

  // small reduction scratch reuses head of C1p..EG1e region? No: dedicated
  // tiny arrays live at the end of s001b region — use separate offsets:
  float* rmp110 = w + OFF_S001B + 24576;           // 1024
  float* rmg110 = rmp110 + 1024;                   // 128
  float* rme011 = rmg110 + 128;                    // 512
  float* rmg011 = rme011 + 512;                    // 384

  k_in_reduce<<<8, 256, 0, stream>>>(x110, x011, rmp110, rmg110, rme011, rmg011);
  k_UV0<<<14336, 256, 0, stream>>>(x110, x011, x001, W0_110, b0_110, W0_011,
                                   b0_011, W0_001, b0_001,
                                   rmp110, rmg110, rme011, rmg011, U0, V0);
  k_post0<<<256, 256, 0, stream>>>(U0, V0, s110, maxpU0, mp110, mg110, s001a);
  k_sg<<<240, 256, 0, stream>>>(W1, mp110, mg110, s001a, C1p, BF1g, EG1e);
  k_V1U1<<<384, 256, 0, stream>>>(V0, maxpU0, s110, W1, b1, C1p, BF1g, EG1e,
                                  U1, V1);
  k_post1<<<256, 256, 0, stream>>>(U1, V1, m110, m011e, s001b);
  k_final<<<4, 128, 0, stream>>>(m110, m011e, s001b, Wact, bact, Wcrit, bcrit, out);
}

// Round 4
// 104.700 us; speedup vs baseline: 2.1771x; 1.2002x over previous
//
#include <hip/hip_runtime.h>
#include <math.h>

#define DEVI __device__ __forceinline__

constexpr int B = 2, P = 16, G = 128, E = 96, N = 128, CO = 2;

DEVI float lrelu(float x) { return x > 0.f ? x : 0.01f * x; }

// ---- workspace layout (floats) ----
constexpr int OFF_U1     = 0;                       // B*N*P*G = 524288
constexpr int OFF_V1     = OFF_U1 + 524288;         // B*N*G*E = 3145728
constexpr int OFF_MAXPU0 = OFF_V1 + 3145728;        // B*N*G = 32768
constexpr int OFF_MAXEV0 = OFF_MAXPU0 + 32768;      // 32768
constexpr int OFF_MP110  = OFF_MAXEV0 + 32768;      // 32768 (== me011)
constexpr int OFF_MG110  = OFF_MP110 + 32768;       // B*N*P = 4096
constexpr int OFF_S001A  = OFF_MG110 + 4096;        // B*N*E = 24576 (== mg011)
constexpr int OFF_RMP    = OFF_S001A + 24576;       // B*4*G = 1024
constexpr int OFF_RMG    = OFF_RMP + 1024;          // B*4*P = 128
constexpr int OFF_RME    = OFF_RMG + 128;           // B*2*G = 512
constexpr int OFF_RMG011 = OFF_RME + 512;           // B*2*E = 384
constexpr int OFF_C1P    = OFF_RMG011 + 384;        // 4096
constexpr int OFF_BF1G   = OFF_C1P + 4096;          // 32768
constexpr int OFF_EG1E   = OFF_BF1G + 32768;        // 24576
constexpr int OFF_M110   = OFF_EG1E + 24576;        // 4096
constexpr int OFF_M011E  = OFF_M110 + 4096;         // 24576
constexpr int OFF_S001B  = OFF_M011E + 24576;       // 24576

// ---------------------------------------------------------------------------
// K1: fused layer 0, one block per (b,n). Recomputes U0/V0 rows in LDS from
// the (L2-resident) raw inputs; writes only small reduction outputs.
__global__ void __launch_bounds__(256) k_layer0(
    const float* __restrict__ x110, const float* __restrict__ x011,
    const float* __restrict__ x001,
    const float* __restrict__ W0_110, const float* __restrict__ b0_110,
    const float* __restrict__ W0_011, const float* __restrict__ b0_011,
    const float* __restrict__ W0_001, const float* __restrict__ b0_001,
    float* __restrict__ maxpU0g, float* __restrict__ maxeV0g,
    float* __restrict__ mp110, float* __restrict__ mg110,
    float* __restrict__ s001a,
    float* __restrict__ rmpG, float* __restrict__ rmgG,
    float* __restrict__ rmeG, float* __restrict__ rmg011G) {
  __shared__ float xs[4 * 16 * 128];     // x110[b]  (c,p,g)  32KB
  __shared__ float v0[128 * 97];         // V0 row (g,e) pitch 97  ~48.5KB
  __shared__ float u0[16 * 128];         // U0 row (p,g)  8KB
  __shared__ float rmp[4 * 128], rmgS[4 * 16], rme[2 * 128], rmg011L[2 * 96];
  __shared__ float mpu[128], mev[128], part[256];
  const int bn = blockIdx.x, b = bn >> 7, n = bn & 127, tid = threadIdx.x;

  // stage x110[b] (8192 floats)
  {
    const float4* xsrc = (const float4*)(x110 + (size_t)b * 8192);
    float4* xdst = (float4*)xs;
#pragma unroll
    for (int k = 0; k < 8; k++) xdst[tid + k * 256] = xsrc[tid + k * 256];
  }
  __syncthreads();
  // input reductions (redundant per block; all sources L2-hot)
  for (int i = tid; i < 512; i += 256) {       // rmp[c][g] = max_p
    int c = i >> 7, g = i & 127;
    float m = -INFINITY;
    for (int p = 0; p < P; p++) m = fmaxf(m, xs[(c * 16 + p) * 128 + g]);
    rmp[i] = m;
  }
  if (tid < 64) {                              // rmgS[c][p] = max_g
    int c = tid >> 4, p = tid & 15;
    float m = -INFINITY;
    for (int g = 0; g < G; g++) m = fmaxf(m, xs[(c * 16 + p) * 128 + g]);
    rmgS[tid] = m;
  }
  {                                            // rme[c][g] = max_e x011
    int c = tid >> 7, g = tid & 127;
    const float4* r = (const float4*)(x011 + ((size_t)(b * 2 + c) * 128 + g) * 96);
    float m = -INFINITY;
#pragma unroll
    for (int j = 0; j < 24; j++) {
      float4 v = r[j];
      m = fmaxf(m, fmaxf(fmaxf(v.x, v.y), fmaxf(v.z, v.w)));
    }
    rme[tid] = m;
  }
  if (tid < 192) {                             // rmg011L[c][e] = max_g x011
    int c = tid / 96, e = tid % 96;
    const float* pp = x011 + ((size_t)(b * 2 + c) * 128) * 96 + e;
    float m = -INFINITY;
    for (int g = 0; g < G; g++) m = fmaxf(m, pp[g * 96]);
    rmg011L[tid] = m;
  }
  __syncthreads();
  // per-n weights (wave-uniform scalars)
  float w0[4], w1[4], w2[4];
#pragma unroll
  for (int cc = 0; cc < 4; cc++) {
    w0[cc] = W0_110[n * 4 + cc];
    w1[cc] = W0_110[512 + n * 4 + cc];
    w2[cc] = W0_110[1024 + n * 4 + cc];
  }
  float we0 = W0_011[512 + n * 2], we1 = W0_011[512 + n * 2 + 1];
  float bu = b0_110[n] + b0_110[128 + n] + b0_110[256 + n] + b0_011[256 + n];
  float vw00 = W0_011[n * 2], vw01 = W0_011[n * 2 + 1];
  float vw10 = W0_011[256 + n * 2], vw11 = W0_011[256 + n * 2 + 1];
  float w001 = W0_001[n];
  float bv = b0_011[n] + b0_011[128 + n] + b0_001[n];

  // U0 row (2048)
#pragma unroll
  for (int k = 0; k < 8; k++) {
    int i = tid + k * 256, p = i >> 7, g = i & 127;
    float acc = bu + we0 * rme[g] + we1 * rme[128 + g];
#pragma unroll
    for (int cc = 0; cc < 4; cc++)
      acc += w0[cc] * xs[(cc * 16 + p) * 128 + g] + w1[cc] * rmp[cc * 128 + g]
           + w2[cc] * rmgS[cc * 16 + p];
    u0[i] = acc;
  }
  // V0 row (12288)
  {
    const float* xa = x011 + (size_t)(b * 2) * 12288;
    const float* xb = xa + 12288;
    const float* xc = x001 + b * 96;
    for (int k = 0; k < 48; k++) {
      int i = tid + k * 256;
      int g = i / 96, e = i - g * 96;
      float val = bv + vw00 * xa[i] + vw01 * xb[i]
                + vw10 * rmg011L[e] + vw11 * rmg011L[96 + e] + w001 * xc[e];
      v0[g * 97 + e] = val;
    }
  }
  __syncthreads();
  if (tid < 128) {                             // maxpU
    float m = -INFINITY;
    for (int p = 0; p < P; p++) m = fmaxf(m, u0[p * 128 + tid]);
    mpu[tid] = m;
    maxpU0g[bn * 128 + tid] = m;
  }
  {                                            // maxeV partials
    int g = tid & 127, h = tid >> 7;
    const float* r = &v0[g * 97 + h * 48];
    float m = -INFINITY;
    for (int j = 0; j < 48; j++) m = fmaxf(m, r[j]);
    part[tid] = m;
  }
  __syncthreads();
  if (tid < 128) {
    float m = fmaxf(part[tid], part[128 + tid]);
    mev[tid] = m;
    maxeV0g[bn * 128 + tid] = m;
    mp110[bn * 128 + tid] = lrelu(mpu[tid] + m);   // == me011
  }
  __syncthreads();
  {                                            // mg110 partials over g
    int p = tid >> 4, ch = tid & 15;
    float m = -INFINITY;
    for (int g = ch * 8; g < ch * 8 + 8; g++)
      m = fmaxf(m, u0[p * 128 + g] + mev[g]);
    part[tid] = m;
  }
  if (tid < 96) {                              // s001a (== mg011)
    float m = -INFINITY;
    for (int g = 0; g < G; g++) m = fmaxf(m, mpu[g] + v0[g * 97 + tid]);
    s001a[bn * 96 + tid] = lrelu(m);
  }
  __syncthreads();
  if (tid < 16) {
    float m = -INFINITY;
    for (int ch = 0; ch < 16; ch++) m = fmaxf(m, part[tid * 16 + ch]);
    mg110[bn * 16 + tid] = lrelu(m);
  }
  if (n == 0) {                                // publish tiny rm arrays
    for (int i = tid; i < 512; i += 256) rmpG[b * 512 + i] = rmp[i];
    if (tid < 64) rmgG[b * 64 + tid] = rmgS[tid];
    rmeG[b * 256 + tid] = rme[tid];
    if (tid < 192) rmg011G[b * 192 + tid] = rmg011L[tid];
  }
}

// K2: small per-axis GEMMs for layer 1 (identities folded)
__global__ void k_sg(const float* __restrict__ W1, const float* __restrict__ mp110,
                     const float* __restrict__ mg110, const float* __restrict__ s001a,
                     float* __restrict__ C1p, float* __restrict__ BF1g,
                     float* __restrict__ EG1e) {
  int t = blockIdx.x * 256 + threadIdx.x;
  if (t < 4096) {                      // C1p = W1[2] @ mg110
    int p = t & 15, n = (t >> 4) & 127, b = t >> 11;
    float acc = 0.f;
    for (int c = 0; c < N; c++)
      acc += W1[(2 * N + n) * N + c] * mg110[(b * N + c) * P + p];
    C1p[t] = acc;
  } else if (t < 36864) {              // BF1g = (W1[1]+W1[5]) @ mp110
    int i = t - 4096;
    int g = i & 127, n = (i >> 7) & 127, b = i >> 14;
    float acc = 0.f;
    for (int c = 0; c < N; c++)
      acc += (W1[(1 * N + n) * N + c] + W1[(5 * N + n) * N + c])
             * mp110[(b * N + c) * G + g];
    BF1g[i] = acc;
  } else {                             // EG1e = (W1[4]+W1[6]) @ s001a
    int i = t - 36864;
    int e = i % 96; int r = i / 96; int n = r & 127, b = r >> 7;
    float acc = 0.f;
    for (int c = 0; c < N; c++)
      acc += (W1[(4 * N + n) * N + c] + W1[(6 * N + n) * N + c])
             * s001a[(b * N + c) * E + e];
    EG1e[i] = acc;
  }
}

// K3: fused layer-1 GEMMs, one block per (b,g,n-half). Recomputes the s110/
// s011 operand columns in LDS from raw inputs + layer-0 reductions.
__global__ void __launch_bounds__(256) k_layer1(
    const float* __restrict__ x110, const float* __restrict__ x011,
    const float* __restrict__ x001,
    const float* __restrict__ W0_110, const float* __restrict__ b0_110,
    const float* __restrict__ W0_011, const float* __restrict__ b0_011,
    const float* __restrict__ W0_001, const float* __restrict__ b0_001,
    const float* __restrict__ maxpU0g, const float* __restrict__ maxeV0g,
    const float* __restrict__ rmpG, const float* __restrict__ rmgG,
    const float* __restrict__ rmeG, const float* __restrict__ rmg011G,
    const float* __restrict__ W1, const float* __restrict__ b1,
    const float* __restrict__ C1p, const float* __restrict__ BF1g,
    const float* __restrict__ EG1e,
    float* __restrict__ U1, float* __restrict__ V1) {
  __shared__ float s110c[128 * 16];        // (c,p)  8KB
  __shared__ float s011c[128 * 96];        // (c,e)  48KB
  __shared__ float W0L110[1536], W0L011[768], W0L001[128];   // FIX: 768 (was 512)
  __shared__ float busum[128], bvsum[128], mpu[128], mev[128];
  __shared__ float x011row[192], rmg011s[192], x001s[96];
  __shared__ float x110col[64], rmg110p[64], rmp4[4], rme2[2];
  const int blk = blockIdx.x;
  const int b = blk >> 8, g = (blk >> 1) & 127, nh = blk & 1;
  const int n0 = nh * 64;
  const int tid = threadIdx.x;

  for (int i = tid; i < 1536; i += 256) W0L110[i] = W0_110[i];
  for (int i = tid; i < 768; i += 256) W0L011[i] = W0_011[i];   // FIX: full 768
  if (tid < 128) {
    W0L001[tid] = W0_001[tid];
    busum[tid] = b0_110[tid] + b0_110[128 + tid] + b0_110[256 + tid] + b0_011[256 + tid];
    bvsum[tid] = b0_011[tid] + b0_011[128 + tid] + b0_001[tid];
    mpu[tid] = maxpU0g[(b * 128 + tid) * 128 + g];
    mev[tid] = maxeV0g[(b * 128 + tid) * 128 + g];
  }
  if (tid < 192) {
    int c = tid / 96, e = tid % 96;
    x011row[tid] = x011[((size_t)(b * 2 + c) * 128 + g) * 96 + e];
    rmg011s[tid] = rmg011G[b * 192 + tid];
  }
  if (tid < 96) x001s[tid] = x001[b * 96 + tid];
  if (tid < 64) {
    int c = tid >> 4, p = tid & 15;
    x110col[tid] = x110[((size_t)(b * 4 + c) * 16 + p) * 128 + g];
    rmg110p[tid] = rmgG[b * 64 + tid];
  }
  if (tid < 4) rmp4[tid] = rmpG[(b * 4 + tid) * 128 + g];
  if (tid < 2) rme2[tid] = rmeG[(b * 2 + tid) * 128 + g];
  __syncthreads();

  // s110 column (c,p) at this g
#pragma unroll
  for (int k = 0; k < 8; k++) {
    int i = tid + k * 256, c = i >> 4, p = i & 15;
    float acc = busum[c] + W0L011[512 + c * 2] * rme2[0]
              + W0L011[512 + c * 2 + 1] * rme2[1];
#pragma unroll
    for (int cc = 0; cc < 4; cc++)
      acc += W0L110[c * 4 + cc] * x110col[cc * 16 + p]
           + W0L110[512 + c * 4 + cc] * rmp4[cc]
           + W0L110[1024 + c * 4 + cc] * rmg110p[cc * 16 + p];
    s110c[i] = lrelu(acc + mev[c]);
  }
  // s011 column (c,e) at this g
  for (int k = 0; k < 48; k++) {
    int i = tid + k * 256;
    int c = i / 96, e = i - c * 96;
    float v = bvsum[c] + W0L011[c * 2] * x011row[e] + W0L011[c * 2 + 1] * x011row[96 + e]
            + W0L011[256 + c * 2] * rmg011s[e] + W0L011[256 + c * 2 + 1] * rmg011s[96 + e]
            + W0L001[c] * x001s[e];
    s011c[i] = lrelu(v + mpu[c]);
  }
  __syncthreads();

  // ---- U1 GEMM: 64n x 16p, K=128 ----
  {
    int nn = tid >> 2, pq = tid & 3;
    int n = n0 + nn;
    float bb = b1[n] + b1[128 + n] + b1[256 + n] + b1[640 + n]
             + BF1g[(b * 128 + n) * 128 + g];
    float4 cp = *(const float4*)&C1p[(b * 128 + n) * 16 + pq * 4];
    float4 a = make_float4(bb + cp.x, bb + cp.y, bb + cp.z, bb + cp.w);
    const float* wr = W1 + (size_t)n * 128;
    for (int c = 0; c < 128; c++) {
      float wv = wr[c];
      float4 s = *(const float4*)&s110c[c * 16 + pq * 4];
      a.x += wv * s.x; a.y += wv * s.y; a.z += wv * s.z; a.w += wv * s.w;
    }
    float* dst = U1 + ((size_t)(b * 128 + n) * 16 + pq * 4) * 128 + g;
    dst[0] = a.x; dst[128] = a.y; dst[256] = a.z; dst[384] = a.w;
  }
  // ---- V1 GEMM: 64n x 96e, K=128 (2n x 12e per thread) ----
  {
    int n2 = tid >> 3, e0 = (tid & 7) * 12;
    int na = n0 + n2 * 2, nb = na + 1;
    float4 aA[3], aB[3];
    {
      float bbA = b1[384 + na] + b1[512 + na] + b1[768 + na];
      float bbB = b1[384 + nb] + b1[512 + nb] + b1[768 + nb];
      const float* egA = EG1e + (b * 128 + na) * 96 + e0;
      const float* egB = EG1e + (b * 128 + nb) * 96 + e0;
#pragma unroll
      for (int k = 0; k < 3; k++) {
        aA[k] = make_float4(bbA + egA[k * 4], bbA + egA[k * 4 + 1],
                            bbA + egA[k * 4 + 2], bbA + egA[k * 4 + 3]);
        aB[k] = make_float4(bbB + egB[k * 4], bbB + egB[k * 4 + 1],
                            bbB + egB[k * 4 + 2], bbB + egB[k * 4 + 3]);
      }
    }
    const float* wA = W1 + (size_t)(384 + na) * 128;
    const float* wB = W1 + (size_t)(384 + nb) * 128;
#pragma unroll 4
    for (int c = 0; c < 128; c++) {
      float4 s0 = *(const float4*)&s011c[c * 96 + e0];
      float4 s1 = *(const float4*)&s011c[c * 96 + e0 + 4];
      float4 s2 = *(const float4*)&s011c[c * 96 + e0 + 8];
      float wa = wA[c], wb = wB[c];
      aA[0].x += wa * s0.x; aA[0].y += wa * s0.y; aA[0].z += wa * s0.z; aA[0].w += wa * s0.w;
      aA[1].x += wa * s1.x; aA[1].y += wa * s1.y; aA[1].z += wa * s1.z; aA[1].w += wa * s1.w;
      aA[2].x += wa * s2.x; aA[2].y += wa * s2.y; aA[2].z += wa * s2.z; aA[2].w += wa * s2.w;
      aB[0].x += wb * s0.x; aB[0].y += wb * s0.y; aB[0].z += wb * s0.z; aB[0].w += wb * s0.w;
      aB[1].x += wb * s1.x; aB[1].y += wb * s1.y; aB[1].z += wb * s1.z; aB[1].w += wb * s1.w;
      aB[2].x += wb * s2.x; aB[2].y += wb * s2.y; aB[2].z += wb * s2.z; aB[2].w += wb * s2.w;
    }
    float* dA = V1 + ((size_t)(b * 128 + na) * 128 + g) * 96 + e0;
    float* dB = V1 + ((size_t)(b * 128 + nb) * 128 + g) * 96 + e0;
#pragma unroll
    for (int k = 0; k < 3; k++) {
      *(float4*)(dA + k * 4) = aA[k];
      *(float4*)(dB + k * 4) = aB[k];
    }
  }
}

// K4: per-(b,n) reduction of layer-2 tiles straight to head inputs.
__global__ void __launch_bounds__(256) k_post1(
    const float* __restrict__ U1, const float* __restrict__ V1,
    float* __restrict__ m110, float* __restrict__ m011e,
    float* __restrict__ s001b) {
  __shared__ float uU[P * G];
  __shared__ float part[256];
  __shared__ float smaxeV[G], smaxpU[G];
  const int bn = blockIdx.x;
  const int tid = threadIdx.x;
  const float4* usrc = (const float4*)(U1 + (size_t)bn * P * G);
  float4* udst = (float4*)uU;
  udst[tid] = usrc[tid];
  udst[tid + 256] = usrc[tid + 256];
  {
    int g = tid & 127, h = tid >> 7;
    const float* vrow = V1 + ((size_t)bn * G + g) * E + h * 48;
    float m = -INFINITY;
#pragma unroll
    for (int j = 0; j < 12; j++) {
      float4 v = *(const float4*)(vrow + j * 4);
      m = fmaxf(m, fmaxf(fmaxf(v.x, v.y), fmaxf(v.z, v.w)));
    }
    part[tid] = m;
  }
  __syncthreads();
  if (tid < G) {
    smaxeV[tid] = fmaxf(part[tid], part[tid + 128]);
    float mp = -INFINITY;
    for (int p = 0; p < P; p++) mp = fmaxf(mp, uU[p * G + tid]);
    smaxpU[tid] = mp;
  }
  __syncthreads();
  if (tid < P) {   // m110[p] = mean_g lrelu(U1[p,g] + maxeV1[g])
    float s = 0.f;
    for (int g = 0; g < G; g++) s += lrelu(uU[tid * G + g] + smaxeV[g]);
    m110[bn * P + tid] = s * (1.f / G);
  }
  if (tid < E) {   // m011e = mean_g lrelu(maxpU1+V1) ; s001b = lrelu(max_g(...))
    float s = 0.f, mm = -INFINITY;
    const float* vcol = V1 + (size_t)bn * G * E + tid;
    for (int g = 0; g < G; g++) {
      float pre = smaxpU[g] + vcol[g * E];
      s += lrelu(pre);
      mm = fmaxf(mm, pre);
    }
    m011e[bn * E + tid] = s * (1.f / G);
    s001b[bn * E + tid] = lrelu(mm);
  }
}

// K5: heads. one block per (b,o), 128 threads.
__global__ void __launch_bounds__(128) k_final(const float* __restrict__ m110,
                                               const float* __restrict__ m011e,
                                               const float* __restrict__ s001,
                                               const float* __restrict__ Wact,
                                               const float* __restrict__ bact,
                                               const float* __restrict__ Wcrit,
                                               const float* __restrict__ bcrit,
                                               float* __restrict__ out) {
  __shared__ float sm011[N], sm001[N], scp[P], sce[E], srow[P], scol[E];
  const int bo = blockIdx.x;
  const int o = bo & 1, b = bo >> 1;
  const int t = threadIdx.x;
  {
    float s1 = 0.f, s2 = 0.f;
    const float* p1 = m011e + (b * N + t) * E;
    const float* p2 = s001 + (b * N + t) * E;
    for (int e = 0; e < E; e++) { s1 += p1[e]; s2 += p2[e]; }
    sm011[t] = s1 * (1.f / E);
    sm001[t] = s2 * (1.f / E);
  }
  __syncthreads();
  if (t < P) {
    const float* wa0 = Wact + o * N;
    const float* wa1 = Wact + (1 * CO + o) * N;
    const float* wa2 = Wact + (2 * CO + o) * N;
    const float* wc0 = Wcrit + o * N;
    float a = 0.f, c = 0.f, aa = 0.f;
    for (int n = 0; n < N; n++) {
      float m = m110[(b * N + n) * P + t];
      a += wa0[n] * m;
      c += wc0[n] * m;
      aa += wa1[n] * sm011[n] + wa2[n] * sm001[n];
    }
    float act = a + aa + bact[o] + bact[CO + o] + bact[2 * CO + o];
    out[(b * CO + o) * P + t] = lrelu(act);
    scp[t] = c + bcrit[o];
  } else if (t < P + E) {
    int e = t - P;
    const float* wc1 = Wcrit + (1 * CO + o) * N;
    const float* wc2 = Wcrit + (2 * CO + o) * N;
    float c = 0.f;
    for (int n = 0; n < N; n++)
      c += wc1[n] * m011e[(b * N + n) * E + e] + wc2[n] * s001[(b * N + n) * E + e];
    sce[e] = c + bcrit[CO + o] + bcrit[2 * CO + o];
  }
  __syncthreads();
  if (t < P) {
    float m = -INFINITY;
    for (int e = 0; e < E; e++) m = fmaxf(m, lrelu(scp[t] + sce[e]));
    srow[t] = m;
  } else if (t < P + E) {
    int e = t - P;
    float m = -INFINITY;
    for (int p = 0; p < P; p++) m = fmaxf(m, lrelu(scp[p] + sce[e]));
    scol[e] = m;
  }
  __syncthreads();
  if (t == 0) {
    float v110 = 0.f, v011 = 0.f;
    for (int p = 0; p < P; p++) v110 += srow[p];
    for (int e = 0; e < E; e++) v011 += scol[e];
    out[B * CO * P + b * CO + o] = 2.f + v110 + 2.f * v011;
  }
}

extern "C" void kernel_launch(void* const* d_in, const int* in_sizes, int n_in,
                              void* d_out, int out_size, void* d_ws, size_t ws_size,
                              hipStream_t stream) {
  const float* x110   = (const float*)d_in[0];
  const float* x011   = (const float*)d_in[1];
  const float* x001   = (const float*)d_in[2];
  const float* W0_110 = (const float*)d_in[3];
  const float* b0_110 = (const float*)d_in[4];
  const float* W0_011 = (const float*)d_in[5];
  const float* b0_011 = (const float*)d_in[6];
  const float* W0_001 = (const float*)d_in[7];
  const float* b0_001 = (const float*)d_in[8];
  const float* W1     = (const float*)d_in[9];
  const float* b1     = (const float*)d_in[10];
  const float* Wact   = (const float*)d_in[11];
  const float* bact   = (const float*)d_in[12];
  const float* Wcrit  = (const float*)d_in[13];
  const float* bcrit  = (const float*)d_in[14];
  float* out = (float*)d_out;
  float* w = (float*)d_ws;

  float* U1     = w + OFF_U1;
  float* V1     = w + OFF_V1;
  float* maxpU0 = w + OFF_MAXPU0;
  float* maxeV0 = w + OFF_MAXEV0;
  float* mp110  = w + OFF_MP110;
  float* mg110  = w + OFF_MG110;
  float* s001a  = w + OFF_S001A;
  float* rmpG   = w + OFF_RMP;
  float* rmgG   = w + OFF_RMG;
  float* rmeG   = w + OFF_RME;
  float* rmg011 = w + OFF_RMG011;
  float* C1p    = w + OFF_C1P;
  float* BF1g   = w + OFF_BF1G;
  float* EG1e   = w + OFF_EG1E;
  float* m110   = w + OFF_M110;
  float* m011e  = w + OFF_M011E;
  float* s001b  = w + OFF_S001B;

  k_layer0<<<256, 256, 0, stream>>>(x110, x011, x001, W0_110, b0_110, W0_011,
                                    b0_011, W0_001, b0_001,
                                    maxpU0, maxeV0, mp110, mg110, s001a,
                                    rmpG, rmgG, rmeG, rmg011);
  k_sg<<<240, 256, 0, stream>>>(W1, mp110, mg110, s001a, C1p, BF1g, EG1e);
  k_layer1<<<512, 256, 0, stream>>>(x110, x011, x001, W0_110, b0_110, W0_011,
                                    b0_011, W0_001, b0_001,
                                    maxpU0, maxeV0, rmpG, rmgG, rmeG, rmg011,
                                    W1, b1, C1p, BF1g, EG1e, U1, V1);
  k_post1<<<256, 256, 0, stream>>>(U1, V1, m110, m011e, s001b);
  k_final<<<4, 128, 0, stream>>>(m110, m011e, s001b, Wact, bact, Wcrit, bcrit, out);
}